// Round 6
// baseline (352.674 us; speedup 1.0000x reference)
//
#include <hip/hip_runtime.h>
#include <math.h>

// B=2, H=8, L=2048, E=512, d=64
constexpr int CL = 2048;
constexpr int NROW = 32768;
constexpr float SCALE = 1.0f / 2048.0f;
constexpr float TWO_PI = 6.283185307179586f;

typedef short short8 __attribute__((ext_vector_type(8)));
typedef float floatx4 __attribute__((ext_vector_type(4)));

__device__ inline unsigned short f2bf(float f) {
  union { float f; unsigned u; } c; c.f = f;
  unsigned u = c.u + 0x7FFF + ((c.u >> 16) & 1);
  return (unsigned short)(u >> 16);
}
__device__ inline float bf2f(unsigned short h) {
  union { unsigned u; float f; } c; c.u = ((unsigned)h) << 16;
  return c.f;
}
// XOR swizzle for [rows][64 ushort] LDS tiles: 16B-group g at row r -> g^(r&7).
__device__ inline int sw(int r, int o) {
  return r * 64 + ((((o >> 3) ^ r) & 7) << 3) + (o & 7);
}

// ---------------- workspace ----------------
// floats:  c0s[NROW] | c0z[NROW]
// ushorts: Ch[NROW*64] | Cl[NROW*64] | Bf[2*131072] | Vf[2*2097152]
constexpr size_t F_C0S = 0;
constexpr size_t F_C0Z = F_C0S + NROW;
constexpr size_t F_END = F_C0Z + NROW;
constexpr size_t U_CH  = 0;
constexpr size_t U_CL  = U_CH + (size_t)NROW * 64;
constexpr size_t U_BF  = U_CL + (size_t)NROW * 64;
constexpr size_t U_VF  = U_BF + (size_t)2 * 131072;
constexpr size_t BF_SPLIT = 131072;
constexpr size_t VF_PLANE = 2097152;

// ================================================================ mega launch 1
// blocks [0,64):   Bf basis-fragment table
// blocks [64,576): kv V-fragment build (hi/lo planes)
// blocks [576,1088): fused DFT+coef (k1), twiddles computed into own LDS
__launch_bounds__(256)
__global__ void mega1(const float* __restrict__ q, const float* __restrict__ kin,
                      const float* __restrict__ values,
                      unsigned short* __restrict__ Bf, unsigned short* __restrict__ Vf,
                      unsigned short* __restrict__ Ch, unsigned short* __restrict__ Cl,
                      float* __restrict__ c0s) {
  __shared__ char smem[16640];
  int tid = threadIdx.x;
  int blk = blockIdx.x;
  if (blk < 64) {
    // ---- Bf table: Bf[split][(lt*2+ks)*64+lane][j]
    int gid = blk * 256 + tid;
    int lt = gid >> 7, rem = gid & 127, ks = rem >> 6, lane = rem & 63;
    int qd = lane >> 4, n = lane & 15;
    int t = lt * 16 + n;
    size_t base = ((size_t)((lt * 2 + ks) * 64 + lane)) * 8;
    for (int j = 0; j < 8; ++j) {
      int kr = ks * 32 + qd * 8 + j;
      int freq = (kr < 32) ? (kr + 1) : (kr - 31);
      int ph = (freq * t) & (CL - 1);
      float ang = (float)ph * (TWO_PI / (float)CL);
      float val = (kr < 32) ? cosf(ang) : sinf(ang);
      unsigned short hi = f2bf(val);
      Bf[base + j] = hi;
      Bf[BF_SPLIT + base + j] = f2bf(val - bf2f(hi));
    }
    return;
  }
  if (blk < 576) {
    // ---- kv: V tile [64 s][64 d] -> transpose -> bf16 hi/lo B-frags
    float* Vt = (float*)smem;                    // [64][65]
    int idx = blk - 64;
    int bh = idx >> 5, st = idx & 31;
    int b = bh >> 3, h = bh & 7;
    {
      int sl = tid >> 2, dq = (tid & 3) * 16;
      const float4* src = (const float4*)(values + ((size_t)(b * 2048 + st * 64 + sl)) * 512 + h * 64 + dq);
#pragma unroll
      for (int m = 0; m < 4; ++m) {
        float4 t4 = src[m];
        int base = sl * 65 + dq + m * 4;
        Vt[base] = t4.x; Vt[base + 1] = t4.y; Vt[base + 2] = t4.z; Vt[base + 3] = t4.w;
      }
    }
    __syncthreads();
#pragma unroll
    for (int iter = 0; iter < 2; ++iter) {
      int it = iter * 256 + tid;
      int lane = it & 63, ksp = (it >> 6) & 1, dt = it >> 7;
      int qd = lane >> 4, n = lane & 15;
      int d = dt * 16 + n;
      short8 hi, lo;
#pragma unroll
      for (int j = 0; j < 8; ++j) {
        float f = Vt[(ksp * 32 + qd * 8 + j) * 65 + d];
        unsigned short h2 = f2bf(f);
        hi[j] = (short)h2; lo[j] = (short)f2bf(f - bf2f(h2));
      }
      size_t off = (((size_t)(bh * 32 + st)) * 8 + dt * 2 + ksp) * 512 + lane * 8;
      *(short8*)(Vf + off) = hi;
      *(short8*)(Vf + VF_PLANE + off) = lo;
    }
    return;
  }
  // ---- k1: fused DFT + coef. Block = 8 s x 8 h of one b (64 rows).
  unsigned short* Tws = (unsigned short*)smem;   // 4 planes x 2048
  {
    int g0 = tid * 8;
    int lane_g = (g0 >> 3) & 63, ksp_g = (g0 >> 9) & 1, ct_g = g0 >> 10;
    int f = ct_g * 16 + (lane_g & 15);
    int cb = ksp_g * 32 + ((lane_g >> 4) & 3) * 8;
#pragma unroll
    for (int j = 0; j < 8; ++j) {
      float ang = (float)((f * (cb + j)) & 63) * (TWO_PI / 64.0f);
      float s1, c1;
      sincosf(ang, &s1, &c1);
      float re = c1, im = -s1;
      unsigned short rh = f2bf(re), ih = f2bf(im);
      Tws[g0 + j] = rh;        Tws[2048 + g0 + j] = f2bf(re - bf2f(rh));
      Tws[4096 + g0 + j] = ih; Tws[6144 + g0 + j] = f2bf(im - bf2f(ih));
    }
  }
  __syncthreads();
  int w = tid >> 6, lane = tid & 63, qd = lane >> 4, n = lane & 15;
  int blk1 = blk - 576;
  int b = blk1 >> 8, s0 = (blk1 & 255) * 8;
  int sA = s0 + w * 2 + (n >> 3), hA = n & 7;
  const float* qp = q + ((size_t)(b * 2048 + sA)) * 512 + hA * 64 + qd * 8;
  const float* kp = kin + ((size_t)(b * 2048 + sA)) * 512 + hA * 64 + qd * 8;
  float qv[16], kv[16];
#pragma unroll
  for (int ksp = 0; ksp < 2; ++ksp) {
    float4 a0 = *(const float4*)(qp + ksp * 32);
    float4 a1 = *(const float4*)(qp + ksp * 32 + 4);
    float4 b0 = *(const float4*)(kp + ksp * 32);
    float4 b1 = *(const float4*)(kp + ksp * 32 + 4);
    qv[ksp*8+0]=a0.x; qv[ksp*8+1]=a0.y; qv[ksp*8+2]=a0.z; qv[ksp*8+3]=a0.w;
    qv[ksp*8+4]=a1.x; qv[ksp*8+5]=a1.y; qv[ksp*8+6]=a1.z; qv[ksp*8+7]=a1.w;
    kv[ksp*8+0]=b0.x; kv[ksp*8+1]=b0.y; kv[ksp*8+2]=b0.z; kv[ksp*8+3]=b0.w;
    kv[ksp*8+4]=b1.x; kv[ksp*8+5]=b1.y; kv[ksp*8+6]=b1.z; kv[ksp*8+7]=b1.w;
  }
  // Nyquist f=32: alternating sum
  float aq = 0.0f, ak = 0.0f;
#pragma unroll
  for (int i = 0; i < 16; ++i) {
    float sg = (i & 1) ? -1.0f : 1.0f;
    aq += sg * qv[i]; ak += sg * kv[i];
  }
  aq += __shfl_xor(aq, 16); aq += __shfl_xor(aq, 32);
  ak += __shfl_xor(ak, 16); ak += __shfl_xor(ak, 32);
  short8 Aqh[2], Aql[2], Akh[2], Akl[2];
#pragma unroll
  for (int ksp = 0; ksp < 2; ++ksp) {
#pragma unroll
    for (int j = 0; j < 8; ++j) {
      unsigned short hq = f2bf(qv[ksp*8+j]);
      Aqh[ksp][j] = (short)hq; Aql[ksp][j] = (short)f2bf(qv[ksp*8+j] - bf2f(hq));
      unsigned short hk = f2bf(kv[ksp*8+j]);
      Akh[ksp][j] = (short)hk; Akl[ksp][j] = (short)f2bf(kv[ksp*8+j] - bf2f(hk));
    }
  }
  float lmr[4] = {0,0,0,0};
  float c0v[4] = {0,0,0,0};
  int hC = (qd * 4) & 7;
  int sC = s0 + w * 2 + (qd >> 1);
#pragma unroll
  for (int ct = 0; ct < 2; ++ct) {
    short8 Brh[2], Brl[2], Bih[2], Bil[2];
#pragma unroll
    for (int ksp = 0; ksp < 2; ++ksp) {
      size_t off = (size_t)ct * 1024 + ksp * 512 + lane * 8;
      Brh[ksp] = *(const short8*)(Tws + off);
      Brl[ksp] = *(const short8*)(Tws + 2048 + off);
      Bih[ksp] = *(const short8*)(Tws + 4096 + off);
      Bil[ksp] = *(const short8*)(Tws + 6144 + off);
    }
    floatx4 qre = {0,0,0,0}, qim = {0,0,0,0}, kre = {0,0,0,0}, kim = {0,0,0,0};
#pragma unroll
    for (int ksp = 0; ksp < 2; ++ksp) {
      qre = __builtin_amdgcn_mfma_f32_16x16x32_bf16(Aqh[ksp], Brh[ksp], qre, 0,0,0);
      qre = __builtin_amdgcn_mfma_f32_16x16x32_bf16(Aqh[ksp], Brl[ksp], qre, 0,0,0);
      qre = __builtin_amdgcn_mfma_f32_16x16x32_bf16(Aql[ksp], Brh[ksp], qre, 0,0,0);
      qim = __builtin_amdgcn_mfma_f32_16x16x32_bf16(Aqh[ksp], Bih[ksp], qim, 0,0,0);
      qim = __builtin_amdgcn_mfma_f32_16x16x32_bf16(Aqh[ksp], Bil[ksp], qim, 0,0,0);
      qim = __builtin_amdgcn_mfma_f32_16x16x32_bf16(Aql[ksp], Bih[ksp], qim, 0,0,0);
      kre = __builtin_amdgcn_mfma_f32_16x16x32_bf16(Akh[ksp], Brh[ksp], kre, 0,0,0);
      kre = __builtin_amdgcn_mfma_f32_16x16x32_bf16(Akh[ksp], Brl[ksp], kre, 0,0,0);
      kre = __builtin_amdgcn_mfma_f32_16x16x32_bf16(Akl[ksp], Brh[ksp], kre, 0,0,0);
      kim = __builtin_amdgcn_mfma_f32_16x16x32_bf16(Akh[ksp], Bih[ksp], kim, 0,0,0);
      kim = __builtin_amdgcn_mfma_f32_16x16x32_bf16(Akh[ksp], Bil[ksp], kim, 0,0,0);
      kim = __builtin_amdgcn_mfma_f32_16x16x32_bf16(Akl[ksp], Bih[ksp], kim, 0,0,0);
    }
    float xre[4], xim[4], tre = 0, tim = 0;
#pragma unroll
    for (int r = 0; r < 4; ++r) {
      xre[r] = qre[r] * kre[r] + qim[r] * kim[r];
      xim[r] = qim[r] * kre[r] - qre[r] * kim[r];
      tre += xre[r]; tim += xim[r];
    }
    tre += __shfl_xor(tre, 16);
    tim += __shfl_xor(tim, 16);
    float mre = tre * 0.125f, mim = tim * 0.125f;
#pragma unroll
    for (int r = 0; r < 4; ++r) {
      float yre = xre[r] - mre, yim = xim[r] - mim;
      if (ct == 0 && n == 0) {
        c0v[r] = yre * SCALE;
      } else {
        int f = ct * 16 + n;
        float a = 2.0f * yre * SCALE, bb = -2.0f * yim * SCALE;
        size_t rowid = (size_t)((b * 8 + hC + r) * 2048 + sC);
        unsigned short ah = f2bf(a);
        Ch[rowid * 64 + f - 1] = ah;
        Cl[rowid * 64 + f - 1] = f2bf(a - bf2f(ah));
        unsigned short bh2 = f2bf(bb);
        Ch[rowid * 64 + 32 + f - 1] = bh2;
        Cl[rowid * 64 + 32 + f - 1] = f2bf(bb - bf2f(bh2));
        lmr[r] += fabsf(a) + fabsf(bb);
      }
    }
  }
  float X32 = aq * ak;
  float m32 = X32;
  m32 += __shfl_xor(m32, 1); m32 += __shfl_xor(m32, 2); m32 += __shfl_xor(m32, 4);
  float A32 = 2.0f * (X32 - m32 * 0.125f) * SCALE;
  if (qd == 0) {
    size_t rowid = (size_t)((b * 8 + (n & 7)) * 2048 + s0 + w * 2 + (n >> 3));
    unsigned short ah = f2bf(A32);
    Ch[rowid * 64 + 31] = ah;
    Cl[rowid * 64 + 31] = f2bf(A32 - bf2f(ah));
    Ch[rowid * 64 + 63] = 0;
    Cl[rowid * 64 + 63] = 0;
  }
  float absA32 = fabsf(A32);
#pragma unroll
  for (int r = 0; r < 4; ++r) {
    lmr[r] += __shfl_xor(lmr[r], 1);
    lmr[r] += __shfl_xor(lmr[r], 2);
    lmr[r] += __shfl_xor(lmr[r], 4);
    lmr[r] += __shfl_xor(lmr[r], 8);
  }
  int qb = lane & 48;
#pragma unroll
  for (int r = 0; r < 4; ++r) {
    float a32r = __shfl(absA32, qb + (qb >> 2) + r);
    if (n == 0) {
      float M = fabsf(c0v[r]) + lmr[r] + a32r;
      size_t rowid = (size_t)((b * 8 + hC + r) * 2048 + sC);
      c0s[rowid] = c0v[r] - M;
    }
  }
}

// ---------------------------------------------------------------- k3: c0z = c0 - log(Z)
__launch_bounds__(256)
__global__ void k3_z(const unsigned short* __restrict__ Ch, const unsigned short* __restrict__ Cl,
                     const float* __restrict__ c0s, const unsigned short* __restrict__ Bf,
                     float* __restrict__ c0z) {
  __shared__ float Zl[64];
  int tid = threadIdx.x;
  int w = tid >> 6, lane = tid & 63, q = lane >> 4, n = lane & 15;
  int rowbase = blockIdx.x * 64;
  short8 Ah[4][2], Al[4][2];
#pragma unroll
  for (int c = 0; c < 4; ++c)
#pragma unroll
    for (int ksp = 0; ksp < 2; ++ksp) {
      size_t srow = (size_t)(rowbase + c * 16 + n);
      Ah[c][ksp] = *(const short8*)(Ch + srow * 64 + ksp * 32 + q * 8);
      Al[c][ksp] = *(const short8*)(Cl + srow * 64 + ksp * 32 + q * 8);
    }
  float c0r[4][4], zacc[4][4];
#pragma unroll
  for (int c = 0; c < 4; ++c)
#pragma unroll
    for (int r = 0; r < 4; ++r) {
      c0r[c][r] = c0s[rowbase + c * 16 + q * 4 + r];
      zacc[c][r] = 0.0f;
    }
  if (tid < 64) Zl[tid] = 0.0f;
  const unsigned short* BfL = Bf + BF_SPLIT;
  for (int lt = w; lt < 128; lt += 4) {
    size_t b0 = ((size_t)(lt * 2 + 0) * 64 + lane) * 8;
    size_t b1 = ((size_t)(lt * 2 + 1) * 64 + lane) * 8;
    short8 Bh0 = *(const short8*)(Bf + b0);
    short8 Bh1 = *(const short8*)(Bf + b1);
    short8 Bl0 = *(const short8*)(BfL + b0);
    short8 Bl1 = *(const short8*)(BfL + b1);
#pragma unroll
    for (int c = 0; c < 4; ++c) {
      floatx4 y = {0.f, 0.f, 0.f, 0.f};
      y = __builtin_amdgcn_mfma_f32_16x16x32_bf16(Ah[c][0], Bh0, y, 0, 0, 0);
      y = __builtin_amdgcn_mfma_f32_16x16x32_bf16(Ah[c][1], Bh1, y, 0, 0, 0);
      y = __builtin_amdgcn_mfma_f32_16x16x32_bf16(Ah[c][0], Bl0, y, 0, 0, 0);
      y = __builtin_amdgcn_mfma_f32_16x16x32_bf16(Ah[c][1], Bl1, y, 0, 0, 0);
      y = __builtin_amdgcn_mfma_f32_16x16x32_bf16(Al[c][0], Bh0, y, 0, 0, 0);
      y = __builtin_amdgcn_mfma_f32_16x16x32_bf16(Al[c][1], Bh1, y, 0, 0, 0);
#pragma unroll
      for (int r = 0; r < 4; ++r) zacc[c][r] += __expf(y[r] + c0r[c][r]);
    }
  }
  __syncthreads();
#pragma unroll
  for (int c = 0; c < 4; ++c)
#pragma unroll
    for (int r = 0; r < 4; ++r) {
#pragma unroll
      for (int m = 1; m < 16; m <<= 1) zacc[c][r] += __shfl_xor(zacc[c][r], m, 16);
      if (n == 0) atomicAdd(&Zl[c * 16 + q * 4 + r], zacc[c][r]);
    }
  __syncthreads();
  if (tid < 64) c0z[rowbase + tid] = c0s[rowbase + tid] - __logf(Zl[tid]);
}

// ---------------------------------------------------------------- k4: output (barrier-free)
// Block = (b,h) x 64 l-cols; wave w owns l-16 slice (all 64 s of each tile).
// E-phase: 4 s-subtiles x 6 MFMA -> exp -> wave-PRIVATE LDS (C-layout -> A-layout).
// PV-phase: A = E (own LDS), B = Vf (global, L1-deduped across waves). No __syncthreads.
__launch_bounds__(256, 3)
__global__ void k4_out(const unsigned short* __restrict__ Ch, const unsigned short* __restrict__ Cl,
                       const float* __restrict__ c0z, const unsigned short* __restrict__ Bf,
                       const unsigned short* __restrict__ Vf, float* __restrict__ out) {
  __shared__ unsigned short Ep[4][16 * 64];     // per-wave private [l 16][s 64] swizzled
  int tid = threadIdx.x;
  int w = tid >> 6, lane = tid & 63, qd = lane >> 4, n = lane & 15;
  int bh = blockIdx.x, b = bh >> 3, h = bh & 7;
  int lB = blockIdx.y;                          // l-block of 64
  int ltw = lB * 4 + w;                         // this wave's 16-l tile
  const unsigned short* BfL = Bf + BF_SPLIT;
  const unsigned short* VfL = Vf + VF_PLANE;
  unsigned short* myEp = &Ep[w][0];
  short8 Bbh[2], Bbl[2];
#pragma unroll
  for (int ksp = 0; ksp < 2; ++ksp) {
    size_t bo = ((size_t)(ltw * 2 + ksp) * 64 + lane) * 8;
    Bbh[ksp] = *(const short8*)(Bf + bo);
    Bbl[ksp] = *(const short8*)(BfL + bo);
  }
  floatx4 accv[4];
#pragma unroll
  for (int dt = 0; dt < 4; ++dt) accv[dt] = (floatx4){0.f, 0.f, 0.f, 0.f};

  for (int st = 0; st < 32; ++st) {
    int rowb = bh * 2048 + st * 64;
    // E-phase: all 64 s for this wave's 16 l
#pragma unroll
    for (int st4 = 0; st4 < 4; ++st4) {
      size_t srow = (size_t)(rowb + st4 * 16 + n);
      short8 Ah0 = *(const short8*)(Ch + srow * 64 + qd * 8);
      short8 Ah1 = *(const short8*)(Ch + srow * 64 + 32 + qd * 8);
      short8 Al0 = *(const short8*)(Cl + srow * 64 + qd * 8);
      short8 Al1 = *(const short8*)(Cl + srow * 64 + 32 + qd * 8);
      float4 c04 = *(const float4*)(c0z + rowb + st4 * 16 + qd * 4);
      floatx4 y = {0.f, 0.f, 0.f, 0.f};
      y = __builtin_amdgcn_mfma_f32_16x16x32_bf16(Ah0, Bbh[0], y, 0, 0, 0);
      y = __builtin_amdgcn_mfma_f32_16x16x32_bf16(Ah1, Bbh[1], y, 0, 0, 0);
      y = __builtin_amdgcn_mfma_f32_16x16x32_bf16(Ah0, Bbl[0], y, 0, 0, 0);
      y = __builtin_amdgcn_mfma_f32_16x16x32_bf16(Ah1, Bbl[1], y, 0, 0, 0);
      y = __builtin_amdgcn_mfma_f32_16x16x32_bf16(Al0, Bbh[0], y, 0, 0, 0);
      y = __builtin_amdgcn_mfma_f32_16x16x32_bf16(Al1, Bbh[1], y, 0, 0, 0);
      unsigned short er[4];
      er[0] = f2bf(__expf(y[0] + c04.x));
      er[1] = f2bf(__expf(y[1] + c04.y));
      er[2] = f2bf(__expf(y[2] + c04.z));
      er[3] = f2bf(__expf(y[3] + c04.w));
      uint2 p2;
      p2.x = (unsigned)er[0] | ((unsigned)er[1] << 16);
      p2.y = (unsigned)er[2] | ((unsigned)er[3] << 16);
      // C-layout: l = n, s_local = st4*16 + qd*4 + r  -> private LDS (swizzled)
      *(uint2*)(myEp + sw(n, st4 * 16 + qd * 4)) = p2;
    }
    // A-layout read back (same wave; lgkmcnt ordering, no barrier)
    short8 Ea0 = *(const short8*)(myEp + sw(n, qd * 8));
    short8 Ea1 = *(const short8*)(myEp + sw(n, 32 + qd * 8));
    // PV-phase: all 4 d-tiles (V-frags identical across waves -> L1 hits)
#pragma unroll
    for (int dt = 0; dt < 4; ++dt) {
      size_t vo = (((size_t)(bh * 32 + st)) * 8 + dt * 2) * 512 + lane * 8;
      short8 Vh0 = *(const short8*)(Vf + vo);
      short8 Vh1 = *(const short8*)(Vf + vo + 512);
      short8 Vl0 = *(const short8*)(VfL + vo);
      short8 Vl1 = *(const short8*)(VfL + vo + 512);
      accv[dt] = __builtin_amdgcn_mfma_f32_16x16x32_bf16(Ea0, Vh0, accv[dt], 0, 0, 0);
      accv[dt] = __builtin_amdgcn_mfma_f32_16x16x32_bf16(Ea0, Vl0, accv[dt], 0, 0, 0);
      accv[dt] = __builtin_amdgcn_mfma_f32_16x16x32_bf16(Ea1, Vh1, accv[dt], 0, 0, 0);
      accv[dt] = __builtin_amdgcn_mfma_f32_16x16x32_bf16(Ea1, Vl1, accv[dt], 0, 0, 0);
    }
  }
  // Store: accv[dt] C-layout: d = dt*16 + n, l = lB*64 + w*16 + qd*4 + r
  int lG = lB * 64 + w * 16 + qd * 4;
#pragma unroll
  for (int dt = 0; dt < 4; ++dt) {
    size_t base = ((size_t)((b * 64 + dt * 16 + n) * 8 + h)) * 2048 + lG;
    float4 o4;
    o4.x = accv[dt][0]; o4.y = accv[dt][1]; o4.z = accv[dt][2]; o4.w = accv[dt][3];
    *(float4*)(out + base) = o4;
  }
}

extern "C" void kernel_launch(void* const* d_in, const int* in_sizes, int n_in,
                              void* d_out, int out_size, void* d_ws, size_t ws_size,
                              hipStream_t stream) {
  const float* q = (const float*)d_in[0];
  const float* k = (const float*)d_in[1];
  const float* v = (const float*)d_in[2];
  float* out = (float*)d_out;
  float* ws = (float*)d_ws;
  float* c0s = ws + F_C0S;
  float* c0z = ws + F_C0Z;
  unsigned short* ubase = (unsigned short*)(ws + F_END);
  unsigned short* Ch = ubase + U_CH;
  unsigned short* Cl = ubase + U_CL;
  unsigned short* Bf = ubase + U_BF;
  unsigned short* Vf = ubase + U_VF;

  mega1<<<dim3(1088), dim3(256), 0, stream>>>(q, k, v, Bf, Vf, Ch, Cl, c0s);
  k3_z<<<dim3(512), dim3(256), 0, stream>>>(Ch, Cl, c0s, Bf, c0z);
  k4_out<<<dim3(16, 32), dim3(256), 0, stream>>>(Ch, Cl, c0z, Bf, Vf, out);
}

// Round 7
// 191.179 us; speedup vs baseline: 1.8447x; 1.8447x over previous
//
#include <hip/hip_runtime.h>
#include <math.h>

// B=2, H=8, L=2048, E=512, d=64
constexpr int CL = 2048;
constexpr int NROW = 32768;
constexpr float SCALE = 1.0f / 2048.0f;
constexpr float TWO_PI = 6.283185307179586f;

typedef short short8 __attribute__((ext_vector_type(8)));
typedef float floatx4 __attribute__((ext_vector_type(4)));

__device__ inline unsigned short f2bf(float f) {
  union { float f; unsigned u; } c; c.f = f;
  unsigned u = c.u + 0x7FFF + ((c.u >> 16) & 1);
  return (unsigned short)(u >> 16);
}
__device__ inline float bf2f(unsigned short h) {
  union { unsigned u; float f; } c; c.u = ((unsigned)h) << 16;
  return c.f;
}
// XOR swizzle for [rows][64 ushort] LDS tiles: 16B-group g at row r -> g^(r&7).
__device__ inline int sw(int r, int o) {
  return r * 64 + ((((o >> 3) ^ r) & 7) << 3) + (o & 7);
}

// ---------------- workspace ----------------
constexpr size_t F_C0S = 0;
constexpr size_t F_C0Z = F_C0S + NROW;
constexpr size_t F_END = F_C0Z + NROW;
constexpr size_t U_CH  = 0;
constexpr size_t U_CL  = U_CH + (size_t)NROW * 64;
constexpr size_t U_BF  = U_CL + (size_t)NROW * 64;
constexpr size_t U_VF  = U_BF + (size_t)2 * 131072;
constexpr size_t BF_SPLIT = 131072;
constexpr size_t VF_PLANE = 2097152;

// ================================================================ mega launch 1
// blocks [0,64):   Bf basis-fragment table
// blocks [64,576): kv V-fragment build (hi/lo planes)
// blocks [576,1088): fused DFT+coef, twiddles computed into own LDS
__launch_bounds__(256)
__global__ void mega1(const float* __restrict__ q, const float* __restrict__ kin,
                      const float* __restrict__ values,
                      unsigned short* __restrict__ Bf, unsigned short* __restrict__ Vf,
                      unsigned short* __restrict__ Ch, unsigned short* __restrict__ Cl,
                      float* __restrict__ c0s) {
  __shared__ char smem[16640];
  int tid = threadIdx.x;
  int blk = blockIdx.x;
  if (blk < 64) {
    int gid = blk * 256 + tid;
    int lt = gid >> 7, rem = gid & 127, ks = rem >> 6, lane = rem & 63;
    int qd = lane >> 4, n = lane & 15;
    int t = lt * 16 + n;
    size_t base = ((size_t)((lt * 2 + ks) * 64 + lane)) * 8;
    for (int j = 0; j < 8; ++j) {
      int kr = ks * 32 + qd * 8 + j;
      int freq = (kr < 32) ? (kr + 1) : (kr - 31);
      int ph = (freq * t) & (CL - 1);
      float ang = (float)ph * (TWO_PI / (float)CL);
      float val = (kr < 32) ? cosf(ang) : sinf(ang);
      unsigned short hi = f2bf(val);
      Bf[base + j] = hi;
      Bf[BF_SPLIT + base + j] = f2bf(val - bf2f(hi));
    }
    return;
  }
  if (blk < 576) {
    float* Vt = (float*)smem;                    // [64][65]
    int idx = blk - 64;
    int bh = idx >> 5, st = idx & 31;
    int b = bh >> 3, h = bh & 7;
    {
      int sl = tid >> 2, dq = (tid & 3) * 16;
      const float4* src = (const float4*)(values + ((size_t)(b * 2048 + st * 64 + sl)) * 512 + h * 64 + dq);
#pragma unroll
      for (int m = 0; m < 4; ++m) {
        float4 t4 = src[m];
        int base = sl * 65 + dq + m * 4;
        Vt[base] = t4.x; Vt[base + 1] = t4.y; Vt[base + 2] = t4.z; Vt[base + 3] = t4.w;
      }
    }
    __syncthreads();
#pragma unroll
    for (int iter = 0; iter < 2; ++iter) {
      int it = iter * 256 + tid;
      int lane = it & 63, ksp = (it >> 6) & 1, dt = it >> 7;
      int qd = lane >> 4, n = lane & 15;
      int d = dt * 16 + n;
      short8 hi, lo;
#pragma unroll
      for (int j = 0; j < 8; ++j) {
        float f = Vt[(ksp * 32 + qd * 8 + j) * 65 + d];
        unsigned short h2 = f2bf(f);
        hi[j] = (short)h2; lo[j] = (short)f2bf(f - bf2f(h2));
      }
      size_t off = (((size_t)(bh * 32 + st)) * 8 + dt * 2 + ksp) * 512 + lane * 8;
      *(short8*)(Vf + off) = hi;
      *(short8*)(Vf + VF_PLANE + off) = lo;
    }
    return;
  }
  // ---- fused DFT + coef. Block = 8 s x 8 h of one b (64 rows).
  unsigned short* Tws = (unsigned short*)smem;   // 4 planes x 2048
  {
    int g0 = tid * 8;
    int lane_g = (g0 >> 3) & 63, ksp_g = (g0 >> 9) & 1, ct_g = g0 >> 10;
    int f = ct_g * 16 + (lane_g & 15);
    int cb = ksp_g * 32 + ((lane_g >> 4) & 3) * 8;
#pragma unroll
    for (int j = 0; j < 8; ++j) {
      float ang = (float)((f * (cb + j)) & 63) * (TWO_PI / 64.0f);
      float s1, c1;
      sincosf(ang, &s1, &c1);
      float re = c1, im = -s1;
      unsigned short rh = f2bf(re), ih = f2bf(im);
      Tws[g0 + j] = rh;        Tws[2048 + g0 + j] = f2bf(re - bf2f(rh));
      Tws[4096 + g0 + j] = ih; Tws[6144 + g0 + j] = f2bf(im - bf2f(ih));
    }
  }
  __syncthreads();
  int w = tid >> 6, lane = tid & 63, qd = lane >> 4, n = lane & 15;
  int blk1 = blk - 576;
  int b = blk1 >> 8, s0 = (blk1 & 255) * 8;
  int sA = s0 + w * 2 + (n >> 3), hA = n & 7;
  const float* qp = q + ((size_t)(b * 2048 + sA)) * 512 + hA * 64 + qd * 8;
  const float* kp = kin + ((size_t)(b * 2048 + sA)) * 512 + hA * 64 + qd * 8;
  float qv[16], kv[16];
#pragma unroll
  for (int ksp = 0; ksp < 2; ++ksp) {
    float4 a0 = *(const float4*)(qp + ksp * 32);
    float4 a1 = *(const float4*)(qp + ksp * 32 + 4);
    float4 b0 = *(const float4*)(kp + ksp * 32);
    float4 b1 = *(const float4*)(kp + ksp * 32 + 4);
    qv[ksp*8+0]=a0.x; qv[ksp*8+1]=a0.y; qv[ksp*8+2]=a0.z; qv[ksp*8+3]=a0.w;
    qv[ksp*8+4]=a1.x; qv[ksp*8+5]=a1.y; qv[ksp*8+6]=a1.z; qv[ksp*8+7]=a1.w;
    kv[ksp*8+0]=b0.x; kv[ksp*8+1]=b0.y; kv[ksp*8+2]=b0.z; kv[ksp*8+3]=b0.w;
    kv[ksp*8+4]=b1.x; kv[ksp*8+5]=b1.y; kv[ksp*8+6]=b1.z; kv[ksp*8+7]=b1.w;
  }
  float aq = 0.0f, ak = 0.0f;
#pragma unroll
  for (int i = 0; i < 16; ++i) {
    float sg = (i & 1) ? -1.0f : 1.0f;
    aq += sg * qv[i]; ak += sg * kv[i];
  }
  aq += __shfl_xor(aq, 16); aq += __shfl_xor(aq, 32);
  ak += __shfl_xor(ak, 16); ak += __shfl_xor(ak, 32);
  short8 Aqh[2], Aql[2], Akh[2], Akl[2];
#pragma unroll
  for (int ksp = 0; ksp < 2; ++ksp) {
#pragma unroll
    for (int j = 0; j < 8; ++j) {
      unsigned short hq = f2bf(qv[ksp*8+j]);
      Aqh[ksp][j] = (short)hq; Aql[ksp][j] = (short)f2bf(qv[ksp*8+j] - bf2f(hq));
      unsigned short hk = f2bf(kv[ksp*8+j]);
      Akh[ksp][j] = (short)hk; Akl[ksp][j] = (short)f2bf(kv[ksp*8+j] - bf2f(hk));
    }
  }
  float lmr[4] = {0,0,0,0};
  float c0v[4] = {0,0,0,0};
  int hC = (qd * 4) & 7;
  int sC = s0 + w * 2 + (qd >> 1);
#pragma unroll
  for (int ct = 0; ct < 2; ++ct) {
    short8 Brh[2], Brl[2], Bih[2], Bil[2];
#pragma unroll
    for (int ksp = 0; ksp < 2; ++ksp) {
      size_t off = (size_t)ct * 1024 + ksp * 512 + lane * 8;
      Brh[ksp] = *(const short8*)(Tws + off);
      Brl[ksp] = *(const short8*)(Tws + 2048 + off);
      Bih[ksp] = *(const short8*)(Tws + 4096 + off);
      Bil[ksp] = *(const short8*)(Tws + 6144 + off);
    }
    floatx4 qre = {0,0,0,0}, qim = {0,0,0,0}, kre = {0,0,0,0}, kim = {0,0,0,0};
#pragma unroll
    for (int ksp = 0; ksp < 2; ++ksp) {
      qre = __builtin_amdgcn_mfma_f32_16x16x32_bf16(Aqh[ksp], Brh[ksp], qre, 0,0,0);
      qre = __builtin_amdgcn_mfma_f32_16x16x32_bf16(Aqh[ksp], Brl[ksp], qre, 0,0,0);
      qre = __builtin_amdgcn_mfma_f32_16x16x32_bf16(Aql[ksp], Brh[ksp], qre, 0,0,0);
      qim = __builtin_amdgcn_mfma_f32_16x16x32_bf16(Aqh[ksp], Bih[ksp], qim, 0,0,0);
      qim = __builtin_amdgcn_mfma_f32_16x16x32_bf16(Aqh[ksp], Bil[ksp], qim, 0,0,0);
      qim = __builtin_amdgcn_mfma_f32_16x16x32_bf16(Aql[ksp], Bih[ksp], qim, 0,0,0);
      kre = __builtin_amdgcn_mfma_f32_16x16x32_bf16(Akh[ksp], Brh[ksp], kre, 0,0,0);
      kre = __builtin_amdgcn_mfma_f32_16x16x32_bf16(Akh[ksp], Brl[ksp], kre, 0,0,0);
      kre = __builtin_amdgcn_mfma_f32_16x16x32_bf16(Akl[ksp], Brh[ksp], kre, 0,0,0);
      kim = __builtin_amdgcn_mfma_f32_16x16x32_bf16(Akh[ksp], Bih[ksp], kim, 0,0,0);
      kim = __builtin_amdgcn_mfma_f32_16x16x32_bf16(Akh[ksp], Bil[ksp], kim, 0,0,0);
      kim = __builtin_amdgcn_mfma_f32_16x16x32_bf16(Akl[ksp], Bih[ksp], kim, 0,0,0);
    }
    float xre[4], xim[4], tre = 0, tim = 0;
#pragma unroll
    for (int r = 0; r < 4; ++r) {
      xre[r] = qre[r] * kre[r] + qim[r] * kim[r];
      xim[r] = qim[r] * kre[r] - qre[r] * kim[r];
      tre += xre[r]; tim += xim[r];
    }
    tre += __shfl_xor(tre, 16);
    tim += __shfl_xor(tim, 16);
    float mre = tre * 0.125f, mim = tim * 0.125f;
#pragma unroll
    for (int r = 0; r < 4; ++r) {
      float yre = xre[r] - mre, yim = xim[r] - mim;
      if (ct == 0 && n == 0) {
        c0v[r] = yre * SCALE;
      } else {
        int f = ct * 16 + n;
        float a = 2.0f * yre * SCALE, bb = -2.0f * yim * SCALE;
        size_t rowid = (size_t)((b * 8 + hC + r) * 2048 + sC);
        unsigned short ah = f2bf(a);
        Ch[rowid * 64 + f - 1] = ah;
        Cl[rowid * 64 + f - 1] = f2bf(a - bf2f(ah));
        unsigned short bh2 = f2bf(bb);
        Ch[rowid * 64 + 32 + f - 1] = bh2;
        Cl[rowid * 64 + 32 + f - 1] = f2bf(bb - bf2f(bh2));
        lmr[r] += fabsf(a) + fabsf(bb);
      }
    }
  }
  float X32 = aq * ak;
  float m32 = X32;
  m32 += __shfl_xor(m32, 1); m32 += __shfl_xor(m32, 2); m32 += __shfl_xor(m32, 4);
  float A32 = 2.0f * (X32 - m32 * 0.125f) * SCALE;
  if (qd == 0) {
    size_t rowid = (size_t)((b * 8 + (n & 7)) * 2048 + s0 + w * 2 + (n >> 3));
    unsigned short ah = f2bf(A32);
    Ch[rowid * 64 + 31] = ah;
    Cl[rowid * 64 + 31] = f2bf(A32 - bf2f(ah));
    Ch[rowid * 64 + 63] = 0;
    Cl[rowid * 64 + 63] = 0;
  }
  float absA32 = fabsf(A32);
#pragma unroll
  for (int r = 0; r < 4; ++r) {
    lmr[r] += __shfl_xor(lmr[r], 1);
    lmr[r] += __shfl_xor(lmr[r], 2);
    lmr[r] += __shfl_xor(lmr[r], 4);
    lmr[r] += __shfl_xor(lmr[r], 8);
  }
  int qb = lane & 48;
#pragma unroll
  for (int r = 0; r < 4; ++r) {
    float a32r = __shfl(absA32, qb + (qb >> 2) + r);
    if (n == 0) {
      float M = fabsf(c0v[r]) + lmr[r] + a32r;
      size_t rowid = (size_t)((b * 8 + hC + r) * 2048 + sC);
      c0s[rowid] = c0v[r] - M;
    }
  }
}

// ---------------------------------------------------------------- k3: c0z = c0 - log(Z)
__launch_bounds__(256)
__global__ void k3_z(const unsigned short* __restrict__ Ch, const unsigned short* __restrict__ Cl,
                     const float* __restrict__ c0s, const unsigned short* __restrict__ Bf,
                     float* __restrict__ c0z) {
  __shared__ float Zl[64];
  int tid = threadIdx.x;
  int w = tid >> 6, lane = tid & 63, q = lane >> 4, n = lane & 15;
  int rowbase = blockIdx.x * 64;
  short8 Ah[4][2], Al[4][2];
#pragma unroll
  for (int c = 0; c < 4; ++c)
#pragma unroll
    for (int ksp = 0; ksp < 2; ++ksp) {
      size_t srow = (size_t)(rowbase + c * 16 + n);
      Ah[c][ksp] = *(const short8*)(Ch + srow * 64 + ksp * 32 + q * 8);
      Al[c][ksp] = *(const short8*)(Cl + srow * 64 + ksp * 32 + q * 8);
    }
  float c0r[4][4], zacc[4][4];
#pragma unroll
  for (int c = 0; c < 4; ++c)
#pragma unroll
    for (int r = 0; r < 4; ++r) {
      c0r[c][r] = c0s[rowbase + c * 16 + q * 4 + r];
      zacc[c][r] = 0.0f;
    }
  if (tid < 64) Zl[tid] = 0.0f;
  const unsigned short* BfL = Bf + BF_SPLIT;
  for (int lt = w; lt < 128; lt += 4) {
    size_t b0 = ((size_t)(lt * 2 + 0) * 64 + lane) * 8;
    size_t b1 = ((size_t)(lt * 2 + 1) * 64 + lane) * 8;
    short8 Bh0 = *(const short8*)(Bf + b0);
    short8 Bh1 = *(const short8*)(Bf + b1);
    short8 Bl0 = *(const short8*)(BfL + b0);
    short8 Bl1 = *(const short8*)(BfL + b1);
#pragma unroll
    for (int c = 0; c < 4; ++c) {
      floatx4 y = {0.f, 0.f, 0.f, 0.f};
      y = __builtin_amdgcn_mfma_f32_16x16x32_bf16(Ah[c][0], Bh0, y, 0, 0, 0);
      y = __builtin_amdgcn_mfma_f32_16x16x32_bf16(Ah[c][1], Bh1, y, 0, 0, 0);
      y = __builtin_amdgcn_mfma_f32_16x16x32_bf16(Ah[c][0], Bl0, y, 0, 0, 0);
      y = __builtin_amdgcn_mfma_f32_16x16x32_bf16(Ah[c][1], Bl1, y, 0, 0, 0);
      y = __builtin_amdgcn_mfma_f32_16x16x32_bf16(Al[c][0], Bh0, y, 0, 0, 0);
      y = __builtin_amdgcn_mfma_f32_16x16x32_bf16(Al[c][1], Bh1, y, 0, 0, 0);
#pragma unroll
      for (int r = 0; r < 4; ++r) zacc[c][r] += __expf(y[r] + c0r[c][r]);
    }
  }
  __syncthreads();
#pragma unroll
  for (int c = 0; c < 4; ++c)
#pragma unroll
    for (int r = 0; r < 4; ++r) {
#pragma unroll
      for (int m = 1; m < 16; m <<= 1) zacc[c][r] += __shfl_xor(zacc[c][r], m, 16);
      if (n == 0) atomicAdd(&Zl[c * 16 + q * 4 + r], zacc[c][r]);
    }
  __syncthreads();
  if (tid < 64) c0z[rowbase + tid] = c0s[rowbase + tid] - __logf(Zl[tid]);
}

// ---------------------------------------------------------------- k4: output
// R5 structure (1024 blocks, shared Es, register prefetch) + PV pipelined
// ACROSS the barrier: period t = E(t) -> loadA(t+1) -> PV(t-1) -> loadV(t+1)
// -> barrier. PV consumes last period's Es, so no wave waits on the tile it
// just produced; the single barrier/tile only publishes Es for NEXT period.
#define K4_LOADA(st_, sl_)                                                           \
  do {                                                                               \
    int rz_ = bh * 2048 + (st_) * 64;                                                \
    size_t srow_ = (size_t)(rz_ + w * 16 + n);                                       \
    Ahs[sl_][0] = *(const short8*)(Ch + srow_ * 64 + qd * 8);                        \
    Ahs[sl_][1] = *(const short8*)(Ch + srow_ * 64 + 32 + qd * 8);                   \
    Als[sl_][0] = *(const short8*)(Cl + srow_ * 64 + qd * 8);                        \
    Als[sl_][1] = *(const short8*)(Cl + srow_ * 64 + 32 + qd * 8);                   \
    c0rs[sl_] = *(const float4*)(c0z + rz_ + w * 16 + qd * 4);                       \
  } while (0)

#define K4_LOADV(st_, sl_)                                                           \
  do {                                                                               \
    size_t vo_ = (((size_t)(bh * 32 + (st_))) * 8 + w * 2) * 512 + lane * 8;         \
    Vhs[sl_][0] = *(const short8*)(Vf + vo_);                                        \
    Vhs[sl_][1] = *(const short8*)(Vf + vo_ + 512);                                  \
    Vls[sl_][0] = *(const short8*)(VfL + vo_);                                       \
    Vls[sl_][1] = *(const short8*)(VfL + vo_ + 512);                                 \
  } while (0)

#define K4_PV(sl_)                                                                   \
  do {                                                                               \
    _Pragma("unroll")                                                                \
    for (int ksp_ = 0; ksp_ < 2; ++ksp_) {                                           \
      short8 E0_ = *(const short8*)(&Es[sl_][sw(n, ksp_ * 32 + qd * 8)]);            \
      short8 E1_ = *(const short8*)(&Es[sl_][sw(16 + n, ksp_ * 32 + qd * 8)]);       \
      accv[0] = __builtin_amdgcn_mfma_f32_16x16x32_bf16(E0_, Vhs[sl_][ksp_], accv[0],0,0,0);\
      accv[0] = __builtin_amdgcn_mfma_f32_16x16x32_bf16(E0_, Vls[sl_][ksp_], accv[0],0,0,0);\
      accv[1] = __builtin_amdgcn_mfma_f32_16x16x32_bf16(E1_, Vhs[sl_][ksp_], accv[1],0,0,0);\
      accv[1] = __builtin_amdgcn_mfma_f32_16x16x32_bf16(E1_, Vls[sl_][ksp_], accv[1],0,0,0);\
    }                                                                                \
  } while (0)

#define K4_ITER(st_, sl_, first_, last_)                                             \
  do {                                                                               \
    floatx4 y0 = {0,0,0,0}, y1 = {0,0,0,0};                                          \
    y0 = __builtin_amdgcn_mfma_f32_16x16x32_bf16(Ahs[sl_][0], Bbh[0][0], y0,0,0,0);  \
    y0 = __builtin_amdgcn_mfma_f32_16x16x32_bf16(Ahs[sl_][1], Bbh[0][1], y0,0,0,0);  \
    y0 = __builtin_amdgcn_mfma_f32_16x16x32_bf16(Ahs[sl_][0], Bbl[0][0], y0,0,0,0);  \
    y0 = __builtin_amdgcn_mfma_f32_16x16x32_bf16(Ahs[sl_][1], Bbl[0][1], y0,0,0,0);  \
    y0 = __builtin_amdgcn_mfma_f32_16x16x32_bf16(Als[sl_][0], Bbh[0][0], y0,0,0,0);  \
    y0 = __builtin_amdgcn_mfma_f32_16x16x32_bf16(Als[sl_][1], Bbh[0][1], y0,0,0,0);  \
    y1 = __builtin_amdgcn_mfma_f32_16x16x32_bf16(Ahs[sl_][0], Bbh[1][0], y1,0,0,0);  \
    y1 = __builtin_amdgcn_mfma_f32_16x16x32_bf16(Ahs[sl_][1], Bbh[1][1], y1,0,0,0);  \
    y1 = __builtin_amdgcn_mfma_f32_16x16x32_bf16(Ahs[sl_][0], Bbl[1][0], y1,0,0,0);  \
    y1 = __builtin_amdgcn_mfma_f32_16x16x32_bf16(Ahs[sl_][1], Bbl[1][1], y1,0,0,0);  \
    y1 = __builtin_amdgcn_mfma_f32_16x16x32_bf16(Als[sl_][0], Bbh[1][0], y1,0,0,0);  \
    y1 = __builtin_amdgcn_mfma_f32_16x16x32_bf16(Als[sl_][1], Bbh[1][1], y1,0,0,0);  \
    if (!(last_)) { K4_LOADA((st_) + 1, 1 - (sl_)); }                                \
    float4 cc_ = c0rs[sl_];                                                          \
    unsigned short e0_[4], e1_[4];                                                   \
    e0_[0] = f2bf(__expf(y0[0] + cc_.x)); e0_[1] = f2bf(__expf(y0[1] + cc_.y));      \
    e0_[2] = f2bf(__expf(y0[2] + cc_.z)); e0_[3] = f2bf(__expf(y0[3] + cc_.w));      \
    e1_[0] = f2bf(__expf(y1[0] + cc_.x)); e1_[1] = f2bf(__expf(y1[1] + cc_.y));      \
    e1_[2] = f2bf(__expf(y1[2] + cc_.z)); e1_[3] = f2bf(__expf(y1[3] + cc_.w));      \
    uint2 p0_, p1_;                                                                  \
    p0_.x = (unsigned)e0_[0] | ((unsigned)e0_[1] << 16);                             \
    p0_.y = (unsigned)e0_[2] | ((unsigned)e0_[3] << 16);                             \
    p1_.x = (unsigned)e1_[0] | ((unsigned)e1_[1] << 16);                             \
    p1_.y = (unsigned)e1_[2] | ((unsigned)e1_[3] << 16);                             \
    *(uint2*)(&Es[sl_][sw(n, w * 16 + qd * 4)]) = p0_;                               \
    *(uint2*)(&Es[sl_][sw(16 + n, w * 16 + qd * 4)]) = p1_;                          \
    if (!(first_)) { K4_PV(1 - (sl_)); }                                             \
    if (!(last_)) { K4_LOADV((st_) + 1, 1 - (sl_)); }                                \
    __syncthreads();                                                                 \
  } while (0)

__launch_bounds__(256, 4)
__global__ void k4_out(const unsigned short* __restrict__ Ch, const unsigned short* __restrict__ Cl,
                       const float* __restrict__ c0z, const unsigned short* __restrict__ Bf,
                       const unsigned short* __restrict__ Vf, float* __restrict__ out) {
  __shared__ unsigned short Es[2][32 * 64];
  int tid = threadIdx.x;
  int w = tid >> 6, lane = tid & 63, qd = lane >> 4, n = lane & 15;
  int bh = blockIdx.x, b = bh >> 3, h = bh & 7;
  int l0 = blockIdx.y * 32, lt0 = blockIdx.y * 2;
  const unsigned short* BfL = Bf + BF_SPLIT;
  const unsigned short* VfL = Vf + VF_PLANE;
  short8 Bbh[2][2], Bbl[2][2];
#pragma unroll
  for (int lt = 0; lt < 2; ++lt)
#pragma unroll
    for (int ksp = 0; ksp < 2; ++ksp) {
      size_t bo = ((size_t)((lt0 + lt) * 2 + ksp) * 64 + lane) * 8;
      Bbh[lt][ksp] = *(const short8*)(Bf + bo);
      Bbl[lt][ksp] = *(const short8*)(BfL + bo);
    }
  floatx4 accv[2];
  accv[0] = (floatx4){0.f, 0.f, 0.f, 0.f};
  accv[1] = (floatx4){0.f, 0.f, 0.f, 0.f};
  short8 Ahs[2][2], Als[2][2], Vhs[2][2], Vls[2][2];
  float4 c0rs[2];
  K4_LOADA(0, 0);
  K4_LOADV(0, 0);
  K4_ITER(0, 0, true, false);
  for (int st2 = 0; st2 < 15; ++st2) {
    K4_ITER(2 * st2 + 1, 1, false, false);
    K4_ITER(2 * st2 + 2, 0, false, false);
  }
  K4_ITER(31, 1, false, true);
  K4_PV(1);   // drain: PV of tile 31 (Es[1], V slot 1)
#pragma unroll
  for (int lt = 0; lt < 2; ++lt) {
    size_t base = ((size_t)((b * 64 + w * 16 + n) * 8 + h)) * 2048 + l0 + lt * 16 + qd * 4;
    float4 o4;
    o4.x = accv[lt][0]; o4.y = accv[lt][1]; o4.z = accv[lt][2]; o4.w = accv[lt][3];
    *(float4*)(out + base) = o4;
  }
}

extern "C" void kernel_launch(void* const* d_in, const int* in_sizes, int n_in,
                              void* d_out, int out_size, void* d_ws, size_t ws_size,
                              hipStream_t stream) {
  const float* q = (const float*)d_in[0];
  const float* k = (const float*)d_in[1];
  const float* v = (const float*)d_in[2];
  float* out = (float*)d_out;
  float* ws = (float*)d_ws;
  float* c0s = ws + F_C0S;
  float* c0z = ws + F_C0Z;
  unsigned short* ubase = (unsigned short*)(ws + F_END);
  unsigned short* Ch = ubase + U_CH;
  unsigned short* Cl = ubase + U_CL;
  unsigned short* Bf = ubase + U_BF;
  unsigned short* Vf = ubase + U_VF;

  mega1<<<dim3(1088), dim3(256), 0, stream>>>(q, k, v, Bf, Vf, Ch, Cl, c0s);
  k3_z<<<dim3(512), dim3(256), 0, stream>>>(Ch, Cl, c0s, Bf, c0z);
  k4_out<<<dim3(16, 64), dim3(256), 0, stream>>>(Ch, Cl, c0z, Bf, Vf, out);
}